// Round 1
// baseline (195.414 us; speedup 1.0000x reference)
//
#include <hip/hip_runtime.h>
#include <hip/hip_bf16.h>

// RisingTideAttentionV2: out[m,:] = softmax-ish( exp(-||x_m - p_n|| / efft_n) ) @ V
// M=16384, N=4096, D=128.  d2 = x2[m] + p2[n] - 2*dot(x_m, p_n)
// NEURON_SCALE = 0.05 + 0.75*(1/600) = 0.05125

typedef __attribute__((ext_vector_type(8))) short short8;
typedef __attribute__((ext_vector_type(4))) float f32x4;
typedef __attribute__((ext_vector_type(4))) int   i32x4;

#define MTOT 16384
#define NTOT 4096
#define DD   128
#define BM   64
#define BN   128
#define NITER (NTOT / BN)  // 32

__device__ __forceinline__ short f2bf(float f) {
    unsigned u = __float_as_uint(f);
    unsigned r = (u + 0x7fffu + ((u >> 16) & 1u)) >> 16;
    return (short)r;
}

// ---------------- prep: bf16 P, bf16 V^T, p2[n], c[n] ----------------
__global__ __launch_bounds__(128) void tide_prep(
    const float* __restrict__ pos, const float* __restrict__ val,
    const float* __restrict__ temp,
    short* __restrict__ Pb,   // [N][128] bf16
    short* __restrict__ Vt,   // [128][N] bf16 (transposed values)
    float* __restrict__ p2g,  // [N]
    float* __restrict__ cg)   // [N] = -log2(e)/efft
{
    const int n = blockIdx.x;
    const int d = threadIdx.x;
    float pv = pos[(size_t)n * DD + d];
    float vv = val[(size_t)n * DD + d];
    Pb[(size_t)n * DD + d] = f2bf(pv);
    Vt[(size_t)d * NTOT + n] = f2bf(vv);

    float s = pv * pv;
    #pragma unroll
    for (int o = 1; o < 64; o <<= 1) s += __shfl_xor(s, o);
    __shared__ float red[2];
    if ((d & 63) == 0) red[d >> 6] = s;
    __syncthreads();
    if (d == 0) {
        p2g[n] = red[0] + red[1];
        float efft = (fabsf(temp[n]) + 0.1f) * 0.05125f;
        cg[n] = -1.4426950408889634f / efft;   // exp(-dist/efft) = exp2(dist * cg)
    }
}

// ---------------- main fused kernel ----------------
// grid = M/BM = 256 blocks, 256 threads (4 waves, 16 rows each)
__global__ __launch_bounds__(256) void tide_main(
    const float* __restrict__ x,     // [M][128] f32
    const short* __restrict__ Pb,    // [N][128] bf16
    const short* __restrict__ Vt,    // [128][N] bf16
    const float* __restrict__ p2g,   // [N]
    const float* __restrict__ cg,    // [N]
    float* __restrict__ out)         // [M][128] f32
{
    __shared__ i32x4 lds_p[BN * 8];       // [128 rows][128 bf16] swizzled, 32 KB
    __shared__ i32x4 lds_v[DD * 8];       // [128 d-rows][128 n bf16] swizzled, 32 KB
    __shared__ short lds_w[4 * 16 * BN];  // per-wave 16x128 bf16, swizzled, 16 KB
    __shared__ float lds_x2[BM];

    const int tid  = threadIdx.x;
    const int wid  = tid >> 6;
    const int lane = tid & 63;
    const int lo   = lane & 15;
    const int hi   = lane >> 4;

    const int m0 = blockIdx.x * BM + wid * 16;  // wave's first row

    // ---- prologue: load X rows -> bf16 A-frags (persistent), compute x2 ----
    short8 xf[4];
    float x2p = 0.f;
    #pragma unroll
    for (int kf = 0; kf < 4; ++kf) {
        const float* src = x + (size_t)(m0 + lo) * DD + kf * 32 + hi * 8;
        f32x4 a = *(const f32x4*)src;
        f32x4 b = *(const f32x4*)(src + 4);
        short8 h;
        h[0] = f2bf(a[0]); h[1] = f2bf(a[1]); h[2] = f2bf(a[2]); h[3] = f2bf(a[3]);
        h[4] = f2bf(b[0]); h[5] = f2bf(b[1]); h[6] = f2bf(b[2]); h[7] = f2bf(b[3]);
        xf[kf] = h;
        x2p += a[0]*a[0] + a[1]*a[1] + a[2]*a[2] + a[3]*a[3];
        x2p += b[0]*b[0] + b[1]*b[1] + b[2]*b[2] + b[3]*b[3];
    }
    // reduce over hi groups (each lane covered 32 of 128 k for row m0+lo)
    x2p += __shfl_xor(x2p, 16);
    x2p += __shfl_xor(x2p, 32);
    if (hi == 0) lds_x2[wid * 16 + lo] = x2p;
    __syncthreads();
    float x2r[4];
    #pragma unroll
    for (int r = 0; r < 4; ++r) x2r[r] = lds_x2[wid * 16 + hi * 4 + r];

    f32x4 oacc[8];
    #pragma unroll
    for (int df = 0; df < 8; ++df) oacc[df] = (f32x4){0.f, 0.f, 0.f, 0.f};
    float rsum[4] = {0.f, 0.f, 0.f, 0.f};

    const short* lds_ps = (const short*)lds_p;
    const short* lds_vs = (const short*)lds_v;

    for (int nt = 0; nt < NITER; ++nt) {
        const int n0 = nt * BN;
        __syncthreads();  // previous iter's readers done before overwrite

        // ---- stage P tile [128][128] bf16, XOR-swizzled in 16B chunks ----
        #pragma unroll
        for (int i = 0; i < 8; ++i) {
            int c = tid + 256 * i;          // 0..2047 16B chunks
            int row = c >> 4, c16 = c & 15;
            lds_p[row * 16 + (c16 ^ (row & 7))] =
                *(const i32x4*)(Pb + (size_t)(n0 + row) * DD + c16 * 8);
        }
        // ---- stage V^T tile [128 d][128 n] bf16 ----
        #pragma unroll
        for (int i = 0; i < 8; ++i) {
            int c = tid + 256 * i;
            int row = c >> 4, c16 = c & 15;
            lds_v[row * 16 + (c16 ^ (row & 7))] =
                *(const i32x4*)(Vt + (size_t)row * NTOT + n0 + c16 * 8);
        }
        __syncthreads();

        // per-column params for this lane's columns (col = nf*16 + lo)
        float p2v[8], cv[8];
        #pragma unroll
        for (int nf = 0; nf < 8; ++nf) {
            p2v[nf] = p2g[n0 + nf * 16 + lo];
            cv[nf]  = cg [n0 + nf * 16 + lo];
        }

        // ---- S = X @ P^T (per 16-col fragment), pointwise, W -> LDS ----
        #pragma unroll
        for (int nf = 0; nf < 8; ++nf) {
            f32x4 s = (f32x4){0.f, 0.f, 0.f, 0.f};
            #pragma unroll
            for (int kf = 0; kf < 4; ++kf) {
                int row = nf * 16 + lo;
                const short8 pf = *(const short8*)(lds_ps + row * 128 +
                                    ((kf * 32 + hi * 8) ^ ((row & 7) << 3)));
                s = __builtin_amdgcn_mfma_f32_16x16x32_bf16(xf[kf], pf, s, 0, 0, 0);
            }
            #pragma unroll
            for (int r = 0; r < 4; ++r) {
                float d2 = x2r[r] + p2v[nf] - 2.f * s[r];
                d2 = fmaxf(d2, 0.f);
                float w = exp2f(sqrtf(d2) * cv[nf]);
                rsum[r] += w;
                int wrow = hi * 4 + r;  // C-layout row
                lds_w[wid * 2048 + wrow * 128 +
                      ((nf * 16 + lo) ^ ((wrow & 7) << 3))] = f2bf(w);
            }
        }

        // ---- PV: O += W @ V  (W A-frags from wave-private LDS) ----
        short8 wf[4];
        #pragma unroll
        for (int kf = 0; kf < 4; ++kf) {
            wf[kf] = *(const short8*)(lds_w + wid * 2048 + lo * 128 +
                        ((kf * 32 + hi * 8) ^ ((lo & 7) << 3)));
        }
        #pragma unroll
        for (int df = 0; df < 8; ++df) {
            #pragma unroll
            for (int kf = 0; kf < 4; ++kf) {
                int row = df * 16 + lo;
                const short8 vf = *(const short8*)(lds_vs + row * 128 +
                                    ((kf * 32 + hi * 8) ^ ((row & 7) << 3)));
                oacc[df] = __builtin_amdgcn_mfma_f32_16x16x32_bf16(wf[kf], vf, oacc[df], 0, 0, 0);
            }
        }
    }

    // ---- epilogue: row-sum reduce, normalize, store ----
    #pragma unroll
    for (int r = 0; r < 4; ++r) {
        float s = rsum[r];
        s += __shfl_xor(s, 1);
        s += __shfl_xor(s, 2);
        s += __shfl_xor(s, 4);
        s += __shfl_xor(s, 8);
        rsum[r] = 1.f / (s + 1e-8f);
    }
    #pragma unroll
    for (int df = 0; df < 8; ++df) {
        #pragma unroll
        for (int r = 0; r < 4; ++r) {
            out[(size_t)(m0 + hi * 4 + r) * DD + df * 16 + lo] = oacc[df][r] * rsum[r];
        }
    }
}

extern "C" void kernel_launch(void* const* d_in, const int* in_sizes, int n_in,
                              void* d_out, int out_size, void* d_ws, size_t ws_size,
                              hipStream_t stream) {
    const float* x    = (const float*)d_in[0];  // [8,2048,128]
    const float* pos  = (const float*)d_in[1];  // [4096,128]
    const float* val  = (const float*)d_in[2];  // [4096,128]
    const float* temp = (const float*)d_in[3];  // [4096]
    float* out = (float*)d_out;

    char* ws = (char*)d_ws;
    short* Pb  = (short*)ws;                             // 1 MB
    short* Vt  = (short*)(ws + (1 << 20));               // 1 MB
    float* p2g = (float*)(ws + (2 << 20));               // 16 KB
    float* cg  = (float*)(ws + (2 << 20) + (16 << 10));  // 16 KB

    hipLaunchKernelGGL(tide_prep, dim3(NTOT), dim3(128), 0, stream,
                       pos, val, temp, Pb, Vt, p2g, cg);
    hipLaunchKernelGGL(tide_main, dim3(MTOT / BM), dim3(256), 0, stream,
                       x, Pb, Vt, p2g, cg, out);
}

// Round 2
// 67.457 us; speedup vs baseline: 2.8969x; 2.8969x over previous
//
#include <hip/hip_runtime.h>
#include <hip/hip_bf16.h>

// RisingTideAttentionV2: out[m,:] = norm( exp(-||x_m - p_n|| / efft_n) ) @ V
// M=16384, N=4096, D=128. d2 = x2[m] + p2[n] - 2*dot(x_m,p_n). NEURON_SCALE=0.05125
//
// Note: for this input distribution every weight underflows to exact 0.0f
// (exponents ~ -290), so per-N-tile we block-vote "all weights == 0" and skip
// W staging + PV MFMA + V reads. This is mathematically exact for ANY input
// (skipped tiles contribute exactly 0 to both numerator and denominator).

typedef __attribute__((ext_vector_type(8))) short short8;
typedef __attribute__((ext_vector_type(4))) short short4v;
typedef __attribute__((ext_vector_type(4))) float f32x4;
typedef __attribute__((ext_vector_type(2))) float f32x2;

#define MTOT 16384
#define NTOT 4096
#define DD   128
#define BM   16
#define BN   128
#define NITER (NTOT / BN)  // 32

__device__ __forceinline__ short f2bf(float f) {
    unsigned u = __float_as_uint(f);
    unsigned r = (u + 0x7fffu + ((u >> 16) & 1u)) >> 16;
    return (short)r;
}

// ---------------- prep: bf16 P, bf16 V^T, p2[n], c[n] ----------------
// grid NTOT/4 blocks x 256 threads; wave w handles row n = blockIdx*4 + w
__global__ __launch_bounds__(256) void tide_prep(
    const float* __restrict__ pos, const float* __restrict__ val,
    const float* __restrict__ temp,
    short* __restrict__ Pb,   // [N][128] bf16
    short* __restrict__ Vt,   // [128][N] bf16
    float* __restrict__ p2g,  // [N]
    float* __restrict__ cg)   // [N] = -log2(e)/efft
{
    __shared__ __attribute__((aligned(16))) short lds_t[DD * 4];  // [d][4 n]
    const int wid = threadIdx.x >> 6, lane = threadIdx.x & 63;
    const int n = blockIdx.x * 4 + wid;
    f32x2 pv = *(const f32x2*)(pos + (size_t)n * DD + lane * 2);
    f32x2 vv = *(const f32x2*)(val + (size_t)n * DD + lane * 2);
    unsigned pb = (unsigned)(unsigned short)f2bf(pv[0]) |
                  ((unsigned)(unsigned short)f2bf(pv[1]) << 16);
    *(unsigned*)(Pb + (size_t)n * DD + lane * 2) = pb;
    lds_t[lane * 8 + wid]     = f2bf(vv[0]);   // d = 2*lane
    lds_t[lane * 8 + 4 + wid] = f2bf(vv[1]);   // d = 2*lane+1
    float s = pv[0] * pv[0] + pv[1] * pv[1];
    #pragma unroll
    for (int o = 1; o < 64; o <<= 1) s += __shfl_xor(s, o);
    if (lane == 0) {
        p2g[n] = s;
        float efft = (fabsf(temp[n]) + 0.1f) * 0.05125f;
        cg[n] = -1.4426950408889634f / efft;   // exp(-d/efft) = exp2(d * cg)
    }
    __syncthreads();
    if (threadIdx.x < DD) {  // write Vt row d: 4 n values, coalesced 8B stores
        short4v v4 = *(const short4v*)(lds_t + threadIdx.x * 4);
        *(short4v*)(Vt + (size_t)threadIdx.x * NTOT + blockIdx.x * 4) = v4;
    }
}

// ---------------- main fused kernel ----------------
// grid = M/BM = 1024 blocks, 256 threads (4 waves). Each block: 16 rows x all N.
// Wave w owns n-fragments {2w, 2w+1} of each tile (QK+pointwise) and
// d-fragments {2w, 2w+1} (PV). LDS ~36.6 KB -> 4 blocks/CU -> ~50% occupancy.
__global__ __launch_bounds__(256) void tide_main(
    const float* __restrict__ x,     // [M][128] f32
    const short* __restrict__ Pb,    // [N][128] bf16
    const short* __restrict__ Vt,    // [128][N] bf16
    const float* __restrict__ p2g,   // [N]
    const float* __restrict__ cg,    // [N]
    float* __restrict__ out)         // [M][128] f32
{
    __shared__ __attribute__((aligned(16))) short lds_p[BN * DD];  // 32 KB, swizzled
    __shared__ __attribute__((aligned(16))) short lds_w[16 * BN];  // 4 KB, swizzled
    __shared__ float lds_x2[16];
    __shared__ float lds_rs[4][16];
    __shared__ int lds_flag[4];

    const int tid = threadIdx.x;
    const int wid = tid >> 6, lane = tid & 63;
    const int lo = lane & 15, hi = lane >> 4;
    const int m0 = blockIdx.x * BM;

    // ---- X rows -> persistent bf16 A-frags + row norms ----
    // A-frag (16x16x32): lane holds A[row=lane&15][k = 8*(lane>>4)+j], j=0..7
    short8 xf[4];
    float x2p = 0.f;
    #pragma unroll
    for (int kf = 0; kf < 4; ++kf) {
        const float* src = x + (size_t)(m0 + lo) * DD + kf * 32 + hi * 8;
        f32x4 a = *(const f32x4*)src;
        f32x4 b = *(const f32x4*)(src + 4);
        short8 h;
        h[0] = f2bf(a[0]); h[1] = f2bf(a[1]); h[2] = f2bf(a[2]); h[3] = f2bf(a[3]);
        h[4] = f2bf(b[0]); h[5] = f2bf(b[1]); h[6] = f2bf(b[2]); h[7] = f2bf(b[3]);
        xf[kf] = h;
        x2p += a[0]*a[0] + a[1]*a[1] + a[2]*a[2] + a[3]*a[3]
             + b[0]*b[0] + b[1]*b[1] + b[2]*b[2] + b[3]*b[3];
    }
    x2p += __shfl_xor(x2p, 16);
    x2p += __shfl_xor(x2p, 32);
    if (wid == 0 && hi == 0) lds_x2[lo] = x2p;
    __syncthreads();
    float x2r[4];
    #pragma unroll
    for (int r = 0; r < 4; ++r) x2r[r] = lds_x2[hi * 4 + r];

    f32x4 oacc0 = {0.f,0.f,0.f,0.f}, oacc1 = {0.f,0.f,0.f,0.f};
    float rs[4] = {0.f, 0.f, 0.f, 0.f};

    // staging constants: thread -> chunk c = tid + 256*i; row=c>>4, ch=c&15.
    // LDS[row][ch] = P[row][ch ^ (row&15)]  (linear dest, pre-swizzled source)
    const int r0 = tid >> 4;
    const int swzch = (tid & 15) ^ (r0 & 15);
    const short* psrc0 = Pb + r0 * DD + swzch * 8;
    short* ldst0 = lds_p + tid * 8;

    for (int nt = 0; nt < NITER; ++nt) {
        const short* ps = psrc0 + nt * BN * DD;
        #pragma unroll
        for (int i = 0; i < 8; ++i) {  // 16 rows per step
            __builtin_amdgcn_global_load_lds(
                (const __attribute__((address_space(1))) void*)(ps + i * 2048),
                (__attribute__((address_space(3))) void*)(ldst0 + i * 2048),
                16, 0, 0);
        }
        const int nb = nt * BN + wid * 32 + lo;   // col of frag t=0
        float p2a = p2g[nb], p2b = p2g[nb + 16];
        float ca = cg[nb],  cb = cg[nb + 16];
        __syncthreads();  // P tile ready (vmcnt drained by barrier)

        // ---- QK: S-frags for this wave's two n-fragments ----
        // B-frag: lane holds P[n = lane&15 + base][k = 8*(lane>>4)+j]
        f32x4 s0 = {0.f,0.f,0.f,0.f}, s1 = {0.f,0.f,0.f,0.f};
        const int row0 = wid * 32 + lo;
        #pragma unroll
        for (int kf = 0; kf < 4; ++kf) {
            int q = kf * 4 + hi;   // 16B chunk of k
            short8 pf0 = *(const short8*)(lds_p + row0 * DD + ((q ^ lo) * 8));
            short8 pf1 = *(const short8*)(lds_p + (row0 + 16) * DD + ((q ^ lo) * 8));
            s0 = __builtin_amdgcn_mfma_f32_16x16x32_bf16(xf[kf], pf0, s0, 0, 0, 0);
            s1 = __builtin_amdgcn_mfma_f32_16x16x32_bf16(xf[kf], pf1, s1, 0, 0, 0);
        }

        // ---- pointwise: C-frag row m=hi*4+r, col n=frag base+lo ----
        float w[8];
        int nz = 0;
        #pragma unroll
        for (int r = 0; r < 4; ++r) {
            float d2a = fmaf(s0[r], -2.f, x2r[r] + p2a);
            float d2b = fmaf(s1[r], -2.f, x2r[r] + p2b);
            d2a = fmaxf(d2a, 0.f);
            d2b = fmaxf(d2b, 0.f);
            float wa = exp2f(__builtin_amdgcn_sqrtf(d2a) * ca);
            float wb = exp2f(__builtin_amdgcn_sqrtf(d2b) * cb);
            rs[r] += wa + wb;
            w[r] = wa; w[4 + r] = wb;
            nz |= (wa > 0.f) | (wb > 0.f);
        }
        const int anyw = __any(nz);
        if (lane == 0) lds_flag[wid] = anyw;
        __syncthreads();  // flags ready; also: all lds_p reads of this tile done
        if (lds_flag[0] | lds_flag[1] | lds_flag[2] | lds_flag[3]) {
            // ---- W -> LDS (swizzled), then PV with V direct from L2 ----
            #pragma unroll
            for (int r = 0; r < 4; ++r) {
                int m = hi * 4 + r;
                int sw = (m & 7) << 3;
                lds_w[m * BN + ((wid * 32 + lo) ^ sw)]      = f2bf(w[r]);
                lds_w[m * BN + ((wid * 32 + 16 + lo) ^ sw)] = f2bf(w[4 + r]);
            }
            __syncthreads();
            short8 wf[4];
            #pragma unroll
            for (int kf = 0; kf < 4; ++kf) {
                int q = kf * 4 + hi;
                wf[kf] = *(const short8*)(lds_w + lo * BN + ((q ^ (lo & 7)) * 8));
            }
            const short* vb0 = Vt + (size_t)(wid * 32 + lo) * NTOT + nt * BN + hi * 8;
            const short* vb1 = vb0 + (size_t)16 * NTOT;
            #pragma unroll
            for (int kf = 0; kf < 4; ++kf) {
                short8 v0 = *(const short8*)(vb0 + kf * 32);
                short8 v1 = *(const short8*)(vb1 + kf * 32);
                oacc0 = __builtin_amdgcn_mfma_f32_16x16x32_bf16(wf[kf], v0, oacc0, 0, 0, 0);
                oacc1 = __builtin_amdgcn_mfma_f32_16x16x32_bf16(wf[kf], v1, oacc1, 0, 0, 0);
            }
        }
    }

    // ---- epilogue: combine rsum across lanes + waves, normalize, store ----
    #pragma unroll
    for (int r = 0; r < 4; ++r) {
        float s = rs[r];
        s += __shfl_xor(s, 1);
        s += __shfl_xor(s, 2);
        s += __shfl_xor(s, 4);
        s += __shfl_xor(s, 8);
        rs[r] = s;
    }
    if (lo == 0) {
        #pragma unroll
        for (int r = 0; r < 4; ++r) lds_rs[wid][hi * 4 + r] = rs[r];
    }
    __syncthreads();
    #pragma unroll
    for (int r = 0; r < 4; ++r) {
        int m = hi * 4 + r;
        float tot = lds_rs[0][m] + lds_rs[1][m] + lds_rs[2][m] + lds_rs[3][m];
        float inv = 1.f / (tot + 1e-8f);
        out[(size_t)(m0 + m) * DD + wid * 32 + lo]      = oacc0[r] * inv;
        out[(size_t)(m0 + m) * DD + wid * 32 + 16 + lo] = oacc1[r] * inv;
    }
}

extern "C" void kernel_launch(void* const* d_in, const int* in_sizes, int n_in,
                              void* d_out, int out_size, void* d_ws, size_t ws_size,
                              hipStream_t stream) {
    const float* x    = (const float*)d_in[0];  // [8,2048,128]
    const float* pos  = (const float*)d_in[1];  // [4096,128]
    const float* val  = (const float*)d_in[2];  // [4096,128]
    const float* temp = (const float*)d_in[3];  // [4096]
    float* out = (float*)d_out;

    char* ws = (char*)d_ws;
    short* Pb  = (short*)ws;                             // 1 MB
    short* Vt  = (short*)(ws + (1 << 20));               // 1 MB
    float* p2g = (float*)(ws + (2 << 20));               // 16 KB
    float* cg  = (float*)(ws + (2 << 20) + (16 << 10));  // 16 KB

    hipLaunchKernelGGL(tide_prep, dim3(NTOT / 4), dim3(256), 0, stream,
                       pos, val, temp, Pb, Vt, p2g, cg);
    hipLaunchKernelGGL(tide_main, dim3(MTOT / BM), dim3(256), 0, stream,
                       x, Pb, Vt, p2g, cg, out);
}